// Round 1
// baseline (1645.872 us; speedup 1.0000x reference)
//
#include <hip/hip_runtime.h>
#include <hip/hip_bf16.h>

#define DEV static __device__ __forceinline__

constexpr int BB = 4;        // batches
constexpr int TT = 12;       // timesteps
constexpr int NN = 10000;    // nodes per batch
constexpr int FD = 16;       // input features (8+8)
constexpr int HD = 128;      // hidden
constexpr int NH = 4;        // attn heads
constexpr int DH = 32;       // head dim
constexpr int FF = 256;      // ffn hidden
constexpr int GO = 64;       // gat2 out
constexpr int HR = 24;       // horizon
constexpr int EE = 160000;   // edges per batch
constexpr int MM = BB * NN;  // total nodes

DEV float cv(float x) { return x; }
DEV float cv(__hip_bfloat16 x) { return __bfloat162float(x); }
DEV void st(float* p, float v) { *p = v; }
DEV void st(__hip_bfloat16* p, float v) { *p = __float2bfloat16(v); }
DEV float lrelu(float x) { return x >= 0.f ? x : 0.2f * x; }

// ---------------- dtype detection -------------------------------------------
// fp32 data reinterpreted as bf16: even elements are low-mantissa bits ->
// random exponents, ~46% have |v|>1024. Real bf16 N(0,1) data: all sane.
__global__ void k_detect(const void* x, int* flag)
{
  const __hip_bfloat16* p = (const __hip_bfloat16*)x;
  int sane = 0;
  for (int i = 0; i < 256; ++i) {
    float v = __bfloat162float(p[i]);
    if (fabsf(v) <= 1024.f) sane++;
  }
  *flag = (sane >= 250) ? 1 : 0;  // 1 = bf16 inputs, 0 = fp32 inputs
}

// ---------------- fused transformer (per-node) ------------------------------
DEV void ln_stats(float v, int hf, int j, float* red8, float& mu, float& rstd)
{
  float s = v, s2 = v * v;
  #pragma unroll
  for (int off = 32; off > 0; off >>= 1) {
    s  += __shfl_xor(s, off);
    s2 += __shfl_xor(s2, off);
  }
  int wv = j >> 6;
  __syncthreads();                      // protect red8 from previous use
  if ((j & 63) == 0) { red8[hf*4 + wv*2] = s; red8[hf*4 + wv*2 + 1] = s2; }
  __syncthreads();
  float ts  = red8[hf*4 + 0] + red8[hf*4 + 2];
  float ts2 = red8[hf*4 + 1] + red8[hf*4 + 3];
  mu = ts * (1.f / 128.f);
  float var = ts2 * (1.f / 128.f) - mu * mu;
  rstd = rsqrtf(var + 1e-5f);
}

template<typename TI>
__global__ __launch_bounds__(256) void k_transformer(
    const int* __restrict__ flag, int want,
    const void* xh_, const void* xc_, const void* encW_, const void* encB_,
    const void* Wq_, const void* Wk_, const void* Wv_, const void* Wo_,
    const void* l1g_, const void* l1b_, const void* W1_, const void* fb1_,
    const void* W2_, const void* fb2_, const void* l2g_, const void* l2b_,
    float* __restrict__ hlast)
{
  if (*flag != want) return;
  const TI* xh  = (const TI*)xh_;   const TI* xc  = (const TI*)xc_;
  const TI* encW= (const TI*)encW_; const TI* encB= (const TI*)encB_;
  const TI* Wq  = (const TI*)Wq_;   const TI* Wk  = (const TI*)Wk_;
  const TI* Wv  = (const TI*)Wv_;   const TI* Wo  = (const TI*)Wo_;
  const TI* l1g = (const TI*)l1g_;  const TI* l1b = (const TI*)l1b_;
  const TI* W1  = (const TI*)W1_;   const TI* fb1 = (const TI*)fb1_;
  const TI* W2  = (const TI*)W2_;   const TI* fb2 = (const TI*)fb2_;
  const TI* l2g = (const TI*)l2g_;  const TI* l2b = (const TI*)l2b_;

  __shared__ float xs[2][TT][FD];
  __shared__ float hs[2][TT][HD];
  __shared__ float ks[2][TT][HD];
  __shared__ float vs[2][TT][HD];
  __shared__ float qs[2][HD];
  __shared__ float lgs[2][NH][TT];
  __shared__ float aw[2][NH][TT];
  __shared__ float aos[2][HD];
  __shared__ float h1s[2][HD];
  __shared__ float f1s[2][FF];
  __shared__ float red8[8];

  const int tid = threadIdx.x;
  const int hf = tid >> 7;          // which node of the block's pair
  const int j = tid & 127;          // channel
  const int m = blockIdx.x * 2 + hf;
  const int b = m / NN, n = m - b * NN;

  // load x = concat(x_hist, x_cov)[b, :, n, :]  -> (T, F)
  for (int idx = j; idx < TT * FD; idx += HD) {
    int t = idx >> 4, f = idx & 15;
    float v = (f < 8) ? cv(xh[(((size_t)b*TT + t)*NN + n)*8 + f])
                      : cv(xc[(((size_t)b*TT + t)*NN + n)*8 + (f - 8)]);
    xs[hf][t][f] = v;
  }
  __syncthreads();

  // h[t][j] = x[t] @ encW + encB
  float h11 = 0.f;
  for (int t = 0; t < TT; ++t) {
    float a = cv(encB[j]);
    #pragma unroll
    for (int f = 0; f < FD; ++f) a += xs[hf][t][f] * cv(encW[f*HD + j]);
    hs[hf][t][j] = a;
    h11 = a;                        // keeps t = TT-1 value
  }
  __syncthreads();

  // k,v for all t; q only for last t
  float kacc[TT], vacc[TT];
  #pragma unroll
  for (int t = 0; t < TT; ++t) { kacc[t] = 0.f; vacc[t] = 0.f; }
  float qacc = 0.f;
  for (int i = 0; i < HD; ++i) {
    float wk = cv(Wk[i*HD + j]);
    float wv = cv(Wv[i*HD + j]);
    float wq = cv(Wq[i*HD + j]);
    qacc += hs[hf][TT-1][i] * wq;
    #pragma unroll
    for (int t = 0; t < TT; ++t) {
      float hv = hs[hf][t][i];
      kacc[t] += hv * wk;
      vacc[t] += hv * wv;
    }
  }
  #pragma unroll
  for (int t = 0; t < TT; ++t) { ks[hf][t][j] = kacc[t]; vs[hf][t][j] = vacc[t]; }
  qs[hf][j] = qacc;
  __syncthreads();

  // logits (4 heads x 12 keys), scale 1/sqrt(32)
  if (j < NH * TT) {
    int hh = j / TT, t = j - hh * TT;
    float a = 0.f;
    #pragma unroll
    for (int d = 0; d < DH; ++d) a += qs[hf][hh*DH + d] * ks[hf][t][hh*DH + d];
    lgs[hf][hh][t] = a * 0.17677669529663687f;
  }
  __syncthreads();
  if (j < NH) {
    float mx = -1e30f;
    #pragma unroll
    for (int t = 0; t < TT; ++t) mx = fmaxf(mx, lgs[hf][j][t]);
    float sm = 0.f;
    float ex[TT];
    #pragma unroll
    for (int t = 0; t < TT; ++t) { ex[t] = expf(lgs[hf][j][t] - mx); sm += ex[t]; }
    float inv = 1.f / sm;
    #pragma unroll
    for (int t = 0; t < TT; ++t) aw[hf][j][t] = ex[t] * inv;
  }
  __syncthreads();
  {
    int hh = j >> 5;
    float a = 0.f;
    #pragma unroll
    for (int t = 0; t < TT; ++t) a += aw[hf][hh][t] * vs[hf][t][j];
    aos[hf][j] = a;
  }
  __syncthreads();

  float o = 0.f;
  for (int i = 0; i < HD; ++i) o += aos[hf][i] * cv(Wo[i*HD + j]);
  float r1 = h11 + o;

  float mu, rstd;
  ln_stats(r1, hf, j, red8, mu, rstd);
  float h1 = (r1 - mu) * rstd * cv(l1g[j]) + cv(l1b[j]);
  h1s[hf][j] = h1;
  __syncthreads();

  // FFN
  float a0 = cv(fb1[j]), a1 = cv(fb1[j + HD]);
  for (int i = 0; i < HD; ++i) {
    float hv = h1s[hf][i];
    a0 += hv * cv(W1[i*FF + j]);
    a1 += hv * cv(W1[i*FF + HD + j]);
  }
  f1s[hf][j] = fmaxf(a0, 0.f);
  f1s[hf][j + HD] = fmaxf(a1, 0.f);
  __syncthreads();
  float f2 = cv(fb2[j]);
  for (int c = 0; c < FF; ++c) f2 += f1s[hf][c] * cv(W2[c*HD + j]);
  float r2 = h1 + f2;
  ln_stats(r2, hf, j, red8, mu, rstd);
  hlast[(size_t)m*HD + j] = (r2 - mu) * rstd * cv(l2g[j]) + cv(l2b[j]);
}

// ---------------- GAT1 ------------------------------------------------------
template<typename TI>
__global__ __launch_bounds__(128) void k_gat1_pre(
    const int* __restrict__ flag, int want,
    const float* __restrict__ hlast, const void* gW_, const void* asr_, const void* adr_,
    float* __restrict__ xl, float* __restrict__ s1, float* __restrict__ d1,
    float* __restrict__ acc, float* __restrict__ den)
{
  if (*flag != want) return;
  const TI* gW  = (const TI*)gW_;
  const TI* asr = (const TI*)asr_;
  const TI* adr = (const TI*)adr_;
  __shared__ float hrow[HD];
  int j = threadIdx.x, m = blockIdx.x;
  hrow[j] = hlast[(size_t)m*HD + j];
  __syncthreads();
  float a = 0.f;
  for (int i = 0; i < HD; ++i) a += hrow[i] * cv(gW[i*HD + j]);
  xl[(size_t)m*HD + j] = a;
  acc[(size_t)m*HD + j] = 0.f;
  float pa = a * cv(asr[j]);
  float pb = a * cv(adr[j]);
  #pragma unroll
  for (int off = 16; off > 0; off >>= 1) { pa += __shfl_xor(pa, off); pb += __shfl_xor(pb, off); }
  if ((j & 31) == 0) {
    int h = j >> 5;
    s1[m*NH + h] = pa;
    d1[m*NH + h] = pb;
    den[m*NH + h] = 0.f;
  }
}

// softmax without max-subtraction: alpha == exp(e)/sum(exp(e)) exactly
__global__ __launch_bounds__(256) void k_gat1_edge(
    const int* __restrict__ e0, const int* __restrict__ e1,
    const float* __restrict__ s1, const float* __restrict__ d1,
    const float* __restrict__ xl, float* __restrict__ acc, float* __restrict__ den)
{
  int g = blockIdx.x * 8 + (threadIdx.x >> 5);  // (edge, head) group, 32 lanes
  int lane = threadIdx.x & 31;
  int h = g & 3, e = g >> 2;
  int b = e / EE, i = e - b * EE;
  int src = e0[i] + b * NN;
  int dst = e1[i] + b * NN;
  float eev = expf(lrelu(s1[src*NH + h] + d1[dst*NH + h]));
  if (lane == 0) atomicAdd(&den[dst*NH + h], eev);
  atomicAdd(&acc[(size_t)dst*HD + h*DH + lane],
            eev * xl[(size_t)src*HD + h*DH + lane]);
}

template<typename TI>
__global__ __launch_bounds__(128) void k_gat1_fin(
    const int* __restrict__ flag, int want,
    const float* __restrict__ xl, const float* __restrict__ s1, const float* __restrict__ d1,
    const float* __restrict__ acc, const float* __restrict__ den,
    const void* gb_, float* __restrict__ g1o)
{
  if (*flag != want) return;
  const TI* gb = (const TI*)gb_;
  int j = threadIdx.x, m = blockIdx.x, h = j >> 5;
  float es = expf(lrelu(s1[m*NH + h] + d1[m*NH + h]));     // self loop
  float num = acc[(size_t)m*HD + j] + es * xl[(size_t)m*HD + j];
  float dn = den[m*NH + h] + es + 1e-16f;
  float v = num / dn + cv(gb[j]);
  g1o[(size_t)m*HD + j] = v > 0.f ? v : expm1f(v);         // ELU
}

// ---------------- GAT2 ------------------------------------------------------
template<typename TI>
__global__ __launch_bounds__(64) void k_gat2_pre(
    const int* __restrict__ flag, int want,
    const float* __restrict__ g1o, const void* gW_, const void* asr_, const void* adr_,
    float* __restrict__ xl2, float* __restrict__ s2, float* __restrict__ d2,
    float* __restrict__ acc2, float* __restrict__ den2)
{
  if (*flag != want) return;
  const TI* gW  = (const TI*)gW_;
  const TI* asr = (const TI*)asr_;
  const TI* adr = (const TI*)adr_;
  __shared__ float grow[HD];
  int j = threadIdx.x, m = blockIdx.x;
  grow[j]      = g1o[(size_t)m*HD + j];
  grow[j + 64] = g1o[(size_t)m*HD + j + 64];
  __syncthreads();
  float a = 0.f;
  for (int i = 0; i < HD; ++i) a += grow[i] * cv(gW[i*GO + j]);
  xl2[(size_t)m*GO + j] = a;
  acc2[(size_t)m*GO + j] = 0.f;
  float pa = a * cv(asr[j]);
  float pb = a * cv(adr[j]);
  #pragma unroll
  for (int off = 32; off > 0; off >>= 1) { pa += __shfl_xor(pa, off); pb += __shfl_xor(pb, off); }
  if (j == 0) { s2[m] = pa; d2[m] = pb; den2[m] = 0.f; }
}

__global__ __launch_bounds__(256) void k_gat2_edge(
    const int* __restrict__ e0, const int* __restrict__ e1,
    const float* __restrict__ s2, const float* __restrict__ d2,
    const float* __restrict__ xl2, float* __restrict__ acc2, float* __restrict__ den2)
{
  int e = blockIdx.x * 4 + (threadIdx.x >> 6);  // one edge per 64 lanes
  int lane = threadIdx.x & 63;
  int b = e / EE, i = e - b * EE;
  int src = e0[i] + b * NN;
  int dst = e1[i] + b * NN;
  float eev = expf(lrelu(s2[src] + d2[dst]));
  if (lane == 0) atomicAdd(&den2[dst], eev);
  atomicAdd(&acc2[(size_t)dst*GO + lane], eev * xl2[(size_t)src*GO + lane]);
}

template<typename TI, typename TO>
__global__ __launch_bounds__(64) void k_gat2_fin(
    const int* __restrict__ flag, int want,
    const float* __restrict__ xl2, const float* __restrict__ s2, const float* __restrict__ d2,
    const float* __restrict__ acc2, const float* __restrict__ den2,
    const void* gb_, const void* oW_, const void* ob_, void* y_)
{
  if (*flag != want) return;
  const TI* gb = (const TI*)gb_;
  const TI* oW = (const TI*)oW_;
  const TI* ob = (const TI*)ob_;
  TO* y = (TO*)y_;
  __shared__ float g2s[GO];
  int j = threadIdx.x, m = blockIdx.x;
  float es = expf(lrelu(s2[m] + d2[m]));
  float num = acc2[(size_t)m*GO + j] + es * xl2[(size_t)m*GO + j];
  float dn = den2[m] + es + 1e-16f;
  g2s[j] = num / dn + cv(gb[j]);
  __syncthreads();
  if (j < HR) {
    float a = cv(ob[j]);
    #pragma unroll
    for (int o2 = 0; o2 < GO; ++o2) a += g2s[o2] * cv(oW[o2*HR + j]);
    int b = m / NN, n = m - b * NN;
    st(&y[((size_t)b*HR + j)*NN + n], a);
  }
}

// ---------------- launch ----------------------------------------------------
extern "C" void kernel_launch(void* const* d_in, const int* in_sizes, int n_in,
                              void* d_out, int out_size, void* d_ws, size_t ws_size,
                              hipStream_t stream)
{
  const int* ei = (const int*)d_in[2];
  const int* e0 = ei;
  const int* e1 = ei + EE;

  float* ws    = (float*)d_ws;
  float* hlast = ws;                  // 40000*128
  float* xl1   = ws + 5120000;        // 40000*128
  float* acc1  = ws + 10240000;       // 40000*128
  float* s1    = ws + 15360000;       // 40000*4
  float* d1    = ws + 15520000;       // 40000*4
  float* den1  = ws + 15680000;       // 40000*4
  int*   flag  = (int*)(ws + 15840000);

  // phase-2 aliases (lifetimes verified disjoint)
  float* g1o  = hlast;
  float* xl2  = xl1;
  float* acc2 = acc1;
  float* s2 = s1; float* d2 = d1; float* den2 = den1;

  k_detect<<<1, 1, 0, stream>>>(d_in[0], flag);

  k_transformer<__hip_bfloat16><<<MM/2, 256, 0, stream>>>(flag, 1,
      d_in[0], d_in[1], d_in[3], d_in[4], d_in[5], d_in[6], d_in[7], d_in[8],
      d_in[9], d_in[10], d_in[11], d_in[12], d_in[13], d_in[14], d_in[15], d_in[16], hlast);
  k_transformer<float><<<MM/2, 256, 0, stream>>>(flag, 0,
      d_in[0], d_in[1], d_in[3], d_in[4], d_in[5], d_in[6], d_in[7], d_in[8],
      d_in[9], d_in[10], d_in[11], d_in[12], d_in[13], d_in[14], d_in[15], d_in[16], hlast);

  k_gat1_pre<__hip_bfloat16><<<MM, 128, 0, stream>>>(flag, 1, hlast,
      d_in[17], d_in[18], d_in[19], xl1, s1, d1, acc1, den1);
  k_gat1_pre<float><<<MM, 128, 0, stream>>>(flag, 0, hlast,
      d_in[17], d_in[18], d_in[19], xl1, s1, d1, acc1, den1);

  k_gat1_edge<<<(BB*EE*NH)/8, 256, 0, stream>>>(e0, e1, s1, d1, xl1, acc1, den1);

  k_gat1_fin<__hip_bfloat16><<<MM, 128, 0, stream>>>(flag, 1, xl1, s1, d1, acc1, den1, d_in[20], g1o);
  k_gat1_fin<float><<<MM, 128, 0, stream>>>(flag, 0, xl1, s1, d1, acc1, den1, d_in[20], g1o);

  k_gat2_pre<__hip_bfloat16><<<MM, 64, 0, stream>>>(flag, 1, g1o,
      d_in[21], d_in[22], d_in[23], xl2, s2, d2, acc2, den2);
  k_gat2_pre<float><<<MM, 64, 0, stream>>>(flag, 0, g1o,
      d_in[21], d_in[22], d_in[23], xl2, s2, d2, acc2, den2);

  k_gat2_edge<<<(BB*EE)/4, 256, 0, stream>>>(e0, e1, s2, d2, xl2, acc2, den2);

  k_gat2_fin<__hip_bfloat16, __hip_bfloat16><<<MM, 64, 0, stream>>>(flag, 1,
      xl2, s2, d2, acc2, den2, d_in[24], d_in[25], d_in[26], d_out);
  k_gat2_fin<float, float><<<MM, 64, 0, stream>>>(flag, 0,
      xl2, s2, d2, acc2, den2, d_in[24], d_in[25], d_in[26], d_out);
}

// Round 2
// 1645.716 us; speedup vs baseline: 1.0001x; 1.0001x over previous
//
#include <hip/hip_runtime.h>
#include <hip/hip_bf16.h>

#define DEV static __device__ __forceinline__

constexpr int BB = 4;        // batches
constexpr int TT = 12;       // timesteps
constexpr int NN = 10000;    // nodes per batch
constexpr int FD = 16;       // input features (8+8)
constexpr int HD = 128;      // hidden
constexpr int NH = 4;        // attn heads
constexpr int DH = 32;       // head dim
constexpr int FF = 256;      // ffn hidden
constexpr int GO = 64;       // gat2 out
constexpr int HR = 24;       // horizon
constexpr int EE = 160000;   // edges per batch
constexpr int MM = BB * NN;  // total nodes

typedef unsigned short bvec8 __attribute__((ext_vector_type(8)));
typedef float fvec4 __attribute__((ext_vector_type(4)));

DEV float cv(float x) { return x; }
DEV float cv(__hip_bfloat16 x) { return __bfloat162float(x); }
DEV void st(float* p, float v) { *p = v; }
DEV void st(__hip_bfloat16* p, float v) { *p = __float2bfloat16(v); }
DEV float lrelu(float x) { return x >= 0.f ? x : 0.2f * x; }

DEV float b2f(unsigned short u) {
  union { unsigned int i; float f; } x; x.i = ((unsigned int)u) << 16; return x.f;
}
DEV unsigned short f2b(float f) {
  union { float f; unsigned int i; } x; x.f = f;
  unsigned int r = x.i + 0x7FFFu + ((x.i >> 16) & 1u);
  return (unsigned short)(r >> 16);
}

// ---------------- dtype detection -------------------------------------------
__global__ void k_detect(const void* x, int* flag)
{
  const __hip_bfloat16* p = (const __hip_bfloat16*)x;
  int sane = 0;
  for (int i = 0; i < 256; ++i) {
    float v = __bfloat162float(p[i]);
    if (fabsf(v) <= 1024.f) sane++;
  }
  *flag = (sane >= 250) ? 1 : 0;  // 1 = bf16 inputs, 0 = fp32 inputs
}

// ---------------- prep: fold attention weights ------------------------------
// Mt[(h*128+c)*128 + i] = sum_d Wq[i][h*32+d] * Wk[c][h*32+d]
// Pt[j*512 + h*128+i]   = sum_d Wv[i][h*32+d] * Wo[h*32+d][j]
template<typename TI>
__global__ __launch_bounds__(256) void k_prep_mp(
    const int* __restrict__ flag, int want,
    const void* Wq_, const void* Wk_, const void* Wv_, const void* Wo_,
    unsigned short* __restrict__ Mt, unsigned short* __restrict__ Pt)
{
  if (*flag != want) return;
  const TI* Wq = (const TI*)Wq_; const TI* Wk = (const TI*)Wk_;
  const TI* Wv = (const TI*)Wv_; const TI* Wo = (const TI*)Wo_;
  int g = blockIdx.x * 256 + threadIdx.x;
  if (g < 65536) {
    int q = g >> 7, i = g & 127, h = q >> 7, c = q & 127;
    float a = 0.f;
    #pragma unroll 8
    for (int d = 0; d < 32; ++d)
      a += cv(Wq[i*HD + h*DH + d]) * cv(Wk[c*HD + h*DH + d]);
    Mt[g] = f2b(a);
  } else {
    int g2 = g - 65536, jj = g2 >> 9, q = g2 & 511, h = q >> 7, i = q & 127;
    float a = 0.f;
    #pragma unroll 8
    for (int d = 0; d < 32; ++d)
      a += cv(Wv[i*HD + h*DH + d]) * cv(Wo[(h*DH + d)*HD + jj]);
    Pt[g2] = f2b(a);
  }
}

// ---------------- prep: transpose/convert other weights ---------------------
template<typename TI>
__global__ __launch_bounds__(256) void k_prep_w(
    const int* __restrict__ flag, int want,
    const void* encW_, const void* encB_, const void* W1_, const void* fb1_,
    const void* W2_, const void* fb2_,
    const void* l1g_, const void* l1b_, const void* l2g_, const void* l2b_,
    unsigned short* __restrict__ W1t, unsigned short* __restrict__ W2t,
    float* __restrict__ encWf, float* __restrict__ encBf,
    float* __restrict__ fb1f, float* __restrict__ fb2f,
    float* __restrict__ l1gf, float* __restrict__ l1bf,
    float* __restrict__ l2gf, float* __restrict__ l2bf)
{
  if (*flag != want) return;
  const TI* encW = (const TI*)encW_; const TI* encB = (const TI*)encB_;
  const TI* W1 = (const TI*)W1_;     const TI* fb1 = (const TI*)fb1_;
  const TI* W2 = (const TI*)W2_;     const TI* fb2 = (const TI*)fb2_;
  const TI* l1g = (const TI*)l1g_;   const TI* l1b = (const TI*)l1b_;
  const TI* l2g = (const TI*)l2g_;   const TI* l2b = (const TI*)l2b_;
  int idx = blockIdx.x * 256 + threadIdx.x;   // 268*256 = 68608 exactly
  if (idx < 32768) {                           // W1t[c][i] = W1[i][c]
    int c = idx >> 7, i = idx & 127;
    W1t[idx] = f2b(cv(W1[i*FF + c]));
  } else if (idx < 65536) {                    // W2t[j][c] = W2[c][j]
    int t = idx - 32768; int jj = t >> 8, c = t & 255;
    W2t[t] = f2b(cv(W2[c*HD + jj]));
  } else if (idx < 67584) { int t = idx - 65536; encWf[t] = cv(encW[t]); }
  else if (idx < 67712)   { int t = idx - 67584; encBf[t] = cv(encB[t]); }
  else if (idx < 67968)   { int t = idx - 67712; fb1f[t] = cv(fb1[t]); }
  else if (idx < 68096)   { int t = idx - 67968; fb2f[t] = cv(fb2[t]); }
  else if (idx < 68224)   { int t = idx - 68096; l1gf[t] = cv(l1g[t]); }
  else if (idx < 68352)   { int t = idx - 68224; l1bf[t] = cv(l1b[t]); }
  else if (idx < 68480)   { int t = idx - 68352; l2gf[t] = cv(l2g[t]); }
  else                    { int t = idx - 68480; l2bf[t] = cv(l2b[t]); }
}

// ---------------- fused transformer (4 nodes/block, 2 nodes/thread) ---------
DEV void ln_pair(float v0, float v1, int tid, float* red,
                 float& mu0, float& rs0, float& mu1, float& rs1)
{
  float s0 = v0, q0 = v0*v0, s1 = v1, q1 = v1*v1;
  #pragma unroll
  for (int off = 32; off > 0; off >>= 1) {
    s0 += __shfl_xor(s0, off); q0 += __shfl_xor(q0, off);
    s1 += __shfl_xor(s1, off); q1 += __shfl_xor(q1, off);
  }
  int half = tid >> 7, wih = (tid >> 6) & 1, lane = tid & 63;
  __syncthreads();
  if (lane == 0) {
    float* p = red + half*8 + wih*4;
    p[0] = s0; p[1] = q0; p[2] = s1; p[3] = q1;
  }
  __syncthreads();
  const float* pa = red + half*8;
  float ts0 = pa[0]+pa[4], tq0 = pa[1]+pa[5];
  float ts1 = pa[2]+pa[6], tq1 = pa[3]+pa[7];
  mu0 = ts0*(1.f/128.f); float va0 = tq0*(1.f/128.f) - mu0*mu0; rs0 = rsqrtf(va0 + 1e-5f);
  mu1 = ts1*(1.f/128.f); float va1 = tq1*(1.f/128.f) - mu1*mu1; rs1 = rsqrtf(va1 + 1e-5f);
}

template<typename TI>
__global__ __launch_bounds__(256) void k_xform(
    const int* __restrict__ flag, int want,
    const void* xh_, const void* xc_,
    const unsigned short* __restrict__ Mt, const unsigned short* __restrict__ Pt,
    const unsigned short* __restrict__ W1t, const unsigned short* __restrict__ W2t,
    const float* __restrict__ encWf, const float* __restrict__ encBf,
    const float* __restrict__ fb1f, const float* __restrict__ fb2f,
    const float* __restrict__ l1gf, const float* __restrict__ l1bf,
    const float* __restrict__ l2gf, const float* __restrict__ l2bf,
    float* __restrict__ hlast)
{
  if (*flag != want) return;
  const TI* xh = (const TI*)xh_;
  const TI* xc = (const TI*)xc_;

  __shared__ unsigned short hsB[4][TT][HD];   // h as bf16
  __shared__ float us[4][512];                // u, then w
  __shared__ float scratch[4][256];           // x, then f1
  __shared__ float h1s[4][HD];
  __shared__ float lgaw[4][NH][TT];           // logits, then alpha
  __shared__ float red[16];

  const int tid = threadIdx.x;
  const int half = tid >> 7;
  const int j = tid & 127;
  const int m0 = blockIdx.x * 4;

  // --- load x (4 nodes x 12 t x 16 f) ---
  #pragma unroll
  for (int k = 0; k < 3; ++k) {
    int idx = tid + k*256;
    int nl = idx / 192, rem = idx - nl*192;
    int t = rem >> 4, f = rem & 15;
    int m = m0 + nl, b = m / NN, n = m - b*NN;
    float v = (f < 8) ? cv(xh[(((size_t)b*TT + t)*NN + n)*8 + f])
                      : cv(xc[(((size_t)b*TT + t)*NN + n)*8 + (f - 8)]);
    scratch[nl][rem] = v;
  }
  __syncthreads();

  // --- encoder: h[t] = x[t] @ encW + encB ---
  float ew[FD];
  #pragma unroll
  for (int f = 0; f < FD; ++f) ew[f] = encWf[f*HD + j];
  float eb = encBf[j];
  float h11[2];
  #pragma unroll
  for (int r = 0; r < 2; ++r) {
    int nl = half*2 + r;
    #pragma unroll
    for (int t = 0; t < TT; ++t) {
      const fvec4* xp = (const fvec4*)&scratch[nl][t*16];
      fvec4 x0 = xp[0], x1 = xp[1], x2 = xp[2], x3 = xp[3];
      float a = eb;
      a += x0[0]*ew[0]  + x0[1]*ew[1]  + x0[2]*ew[2]  + x0[3]*ew[3];
      a += x1[0]*ew[4]  + x1[1]*ew[5]  + x1[2]*ew[6]  + x1[3]*ew[7];
      a += x2[0]*ew[8]  + x2[1]*ew[9]  + x2[2]*ew[10] + x2[3]*ew[11];
      a += x3[0]*ew[12] + x3[1]*ew[13] + x3[2]*ew[14] + x3[3]*ew[15];
      hsB[nl][t][j] = f2b(a);
      if (t == TT-1) h11[r] = a;
    }
  }
  __syncthreads();

  // --- u = h_last @ M (4 heads x 128) ---
  float ua[4][2];
  #pragma unroll
  for (int qi = 0; qi < 4; ++qi) { ua[qi][0] = 0.f; ua[qi][1] = 0.f; }
  for (int i8 = 0; i8 < 16; ++i8) {
    float hv[2][8];
    #pragma unroll
    for (int r = 0; r < 2; ++r) {
      bvec8 hb = *(const bvec8*)&hsB[half*2+r][TT-1][i8*8];
      #pragma unroll
      for (int e = 0; e < 8; ++e) hv[r][e] = b2f(hb[e]);
    }
    #pragma unroll
    for (int qi = 0; qi < 4; ++qi) {
      bvec8 wb = *(const bvec8*)&Mt[(qi*128 + j)*128 + i8*8];
      #pragma unroll
      for (int e = 0; e < 8; ++e) {
        float wf = b2f(wb[e]);
        ua[qi][0] += wf * hv[0][e];
        ua[qi][1] += wf * hv[1][e];
      }
    }
  }
  #pragma unroll
  for (int qi = 0; qi < 4; ++qi) {
    us[half*2+0][qi*128 + j] = ua[qi][0];
    us[half*2+1][qi*128 + j] = ua[qi][1];
  }
  __syncthreads();

  // --- logits: 2 nodes x 4 heads x 12 t per half ---
  if (j < 96) {
    int r = j / 48, p = j - r*48, hd = p / 12, t = p - hd*12;
    int nl = half*2 + r;
    float a = 0.f;
    for (int i = 0; i < HD; ++i)
      a += us[nl][hd*128 + i] * b2f(hsB[nl][t][i]);
    lgaw[nl][hd][t] = a * 0.17677669529663687f;
  }
  __syncthreads();

  // --- softmax over t ---
  if (j < 8) {
    int r = j >> 2, hd = j & 3, nl = half*2 + r;
    float mx = -1e30f;
    #pragma unroll
    for (int t = 0; t < TT; ++t) mx = fmaxf(mx, lgaw[nl][hd][t]);
    float ex[TT], sm = 0.f;
    #pragma unroll
    for (int t = 0; t < TT; ++t) { ex[t] = expf(lgaw[nl][hd][t] - mx); sm += ex[t]; }
    float inv = 1.f / sm;
    #pragma unroll
    for (int t = 0; t < TT; ++t) lgaw[nl][hd][t] = ex[t] * inv;
  }
  __syncthreads();

  // --- w_h = sum_t alpha_ht * h_t (overwrites us) ---
  float wa[4][2];
  #pragma unroll
  for (int hd = 0; hd < 4; ++hd) { wa[hd][0] = 0.f; wa[hd][1] = 0.f; }
  #pragma unroll
  for (int r = 0; r < 2; ++r) {
    int nl = half*2 + r;
    #pragma unroll
    for (int t = 0; t < TT; ++t) {
      float hv = b2f(hsB[nl][t][j]);
      #pragma unroll
      for (int hd = 0; hd < 4; ++hd) wa[hd][r] += lgaw[nl][hd][t] * hv;
    }
  }
  __syncthreads();   // ensure all logits consumed before overwrite
  #pragma unroll
  for (int hd = 0; hd < 4; ++hd) {
    us[half*2+0][hd*128 + j] = wa[hd][0];
    us[half*2+1][hd*128 + j] = wa[hd][1];
  }
  __syncthreads();

  // --- attn-out @ Wo folded: out[j] = sum_q w[q] * Pt[j][q] ---
  float oa[2] = {0.f, 0.f};
  for (int q8 = 0; q8 < 64; ++q8) {
    bvec8 pb = *(const bvec8*)&Pt[j*512 + q8*8];
    float pf[8];
    #pragma unroll
    for (int e = 0; e < 8; ++e) pf[e] = b2f(pb[e]);
    #pragma unroll
    for (int r = 0; r < 2; ++r) {
      const fvec4* wp = (const fvec4*)&us[half*2+r][q8*8];
      fvec4 w0 = wp[0], w1 = wp[1];
      oa[r] += pf[0]*w0[0] + pf[1]*w0[1] + pf[2]*w0[2] + pf[3]*w0[3]
             + pf[4]*w1[0] + pf[5]*w1[1] + pf[6]*w1[2] + pf[7]*w1[3];
    }
  }

  // --- LN1 ---
  float mu0, rs0, mu1, rs1;
  float r1a = h11[0] + oa[0], r1b = h11[1] + oa[1];
  ln_pair(r1a, r1b, tid, red, mu0, rs0, mu1, rs1);
  float g1 = l1gf[j], b1 = l1bf[j];
  float h1a = (r1a - mu0)*rs0*g1 + b1;
  float h1b = (r1b - mu1)*rs1*g1 + b1;
  h1s[half*2+0][j] = h1a;
  h1s[half*2+1][j] = h1b;
  __syncthreads();

  // --- FFN layer 1 (channels j and j+128) ---
  float fa[2][2] = {{0.f,0.f},{0.f,0.f}};
  for (int i8 = 0; i8 < 16; ++i8) {
    float hv[2][8];
    #pragma unroll
    for (int r = 0; r < 2; ++r) {
      const fvec4* hp = (const fvec4*)&h1s[half*2+r][i8*8];
      fvec4 a0 = hp[0], a1 = hp[1];
      hv[r][0]=a0[0]; hv[r][1]=a0[1]; hv[r][2]=a0[2]; hv[r][3]=a0[3];
      hv[r][4]=a1[0]; hv[r][5]=a1[1]; hv[r][6]=a1[2]; hv[r][7]=a1[3];
    }
    bvec8 w0b = *(const bvec8*)&W1t[j*128 + i8*8];
    bvec8 w1b = *(const bvec8*)&W1t[(j+128)*128 + i8*8];
    #pragma unroll
    for (int e = 0; e < 8; ++e) {
      float w0f = b2f(w0b[e]), w1f = b2f(w1b[e]);
      fa[0][0] += w0f*hv[0][e]; fa[0][1] += w0f*hv[1][e];
      fa[1][0] += w1f*hv[0][e]; fa[1][1] += w1f*hv[1][e];
    }
  }
  float bv1 = fb1f[j], bv2 = fb1f[j+128];
  scratch[half*2+0][j]     = fmaxf(fa[0][0] + bv1, 0.f);
  scratch[half*2+1][j]     = fmaxf(fa[0][1] + bv1, 0.f);
  scratch[half*2+0][j+128] = fmaxf(fa[1][0] + bv2, 0.f);
  scratch[half*2+1][j+128] = fmaxf(fa[1][1] + bv2, 0.f);
  __syncthreads();

  // --- FFN layer 2 ---
  float f2a[2] = {0.f, 0.f};
  for (int c8 = 0; c8 < 32; ++c8) {
    bvec8 wb = *(const bvec8*)&W2t[j*256 + c8*8];
    float wf[8];
    #pragma unroll
    for (int e = 0; e < 8; ++e) wf[e] = b2f(wb[e]);
    #pragma unroll
    for (int r = 0; r < 2; ++r) {
      const fvec4* fp = (const fvec4*)&scratch[half*2+r][c8*8];
      fvec4 f0 = fp[0], f1 = fp[1];
      f2a[r] += wf[0]*f0[0] + wf[1]*f0[1] + wf[2]*f0[2] + wf[3]*f0[3]
              + wf[4]*f1[0] + wf[5]*f1[1] + wf[6]*f1[2] + wf[7]*f1[3];
    }
  }
  float fb2v = fb2f[j];
  float r2a = h1a + fb2v + f2a[0];
  float r2b = h1b + fb2v + f2a[1];
  ln_pair(r2a, r2b, tid, red, mu0, rs0, mu1, rs1);
  float g2 = l2gf[j], b2v = l2bf[j];
  hlast[(size_t)(m0 + half*2 + 0)*HD + j] = (r2a - mu0)*rs0*g2 + b2v;
  hlast[(size_t)(m0 + half*2 + 1)*HD + j] = (r2b - mu1)*rs1*g2 + b2v;
}

// ---------------- legacy fp32 transformer (safety path, flag==0) ------------
DEV void ln_stats(float v, int hf, int j, float* red8, float& mu, float& rstd)
{
  float s = v, s2 = v * v;
  #pragma unroll
  for (int off = 32; off > 0; off >>= 1) {
    s  += __shfl_xor(s, off);
    s2 += __shfl_xor(s2, off);
  }
  int wv = j >> 6;
  __syncthreads();
  if ((j & 63) == 0) { red8[hf*4 + wv*2] = s; red8[hf*4 + wv*2 + 1] = s2; }
  __syncthreads();
  float ts  = red8[hf*4 + 0] + red8[hf*4 + 2];
  float ts2 = red8[hf*4 + 1] + red8[hf*4 + 3];
  mu = ts * (1.f / 128.f);
  float var = ts2 * (1.f / 128.f) - mu * mu;
  rstd = rsqrtf(var + 1e-5f);
}

template<typename TI>
__global__ __launch_bounds__(256) void k_transformer(
    const int* __restrict__ flag, int want,
    const void* xh_, const void* xc_, const void* encW_, const void* encB_,
    const void* Wq_, const void* Wk_, const void* Wv_, const void* Wo_,
    const void* l1g_, const void* l1b_, const void* W1_, const void* fb1_,
    const void* W2_, const void* fb2_, const void* l2g_, const void* l2b_,
    float* __restrict__ hlast)
{
  if (*flag != want) return;
  const TI* xh  = (const TI*)xh_;   const TI* xc  = (const TI*)xc_;
  const TI* encW= (const TI*)encW_; const TI* encB= (const TI*)encB_;
  const TI* Wq  = (const TI*)Wq_;   const TI* Wk  = (const TI*)Wk_;
  const TI* Wv  = (const TI*)Wv_;   const TI* Wo  = (const TI*)Wo_;
  const TI* l1g = (const TI*)l1g_;  const TI* l1b = (const TI*)l1b_;
  const TI* W1  = (const TI*)W1_;   const TI* fb1 = (const TI*)fb1_;
  const TI* W2  = (const TI*)W2_;   const TI* fb2 = (const TI*)fb2_;
  const TI* l2g = (const TI*)l2g_;  const TI* l2b = (const TI*)l2b_;

  __shared__ float xs[2][TT][FD];
  __shared__ float hs[2][TT][HD];
  __shared__ float ks[2][TT][HD];
  __shared__ float vs[2][TT][HD];
  __shared__ float qs[2][HD];
  __shared__ float lgs[2][NH][TT];
  __shared__ float aw[2][NH][TT];
  __shared__ float aos[2][HD];
  __shared__ float h1s[2][HD];
  __shared__ float f1s[2][FF];
  __shared__ float red8[8];

  const int tid = threadIdx.x;
  const int hf = tid >> 7;
  const int j = tid & 127;
  const int m = blockIdx.x * 2 + hf;
  const int b = m / NN, n = m - b * NN;

  for (int idx = j; idx < TT * FD; idx += HD) {
    int t = idx >> 4, f = idx & 15;
    float v = (f < 8) ? cv(xh[(((size_t)b*TT + t)*NN + n)*8 + f])
                      : cv(xc[(((size_t)b*TT + t)*NN + n)*8 + (f - 8)]);
    xs[hf][t][f] = v;
  }
  __syncthreads();

  float h11 = 0.f;
  for (int t = 0; t < TT; ++t) {
    float a = cv(encB[j]);
    #pragma unroll
    for (int f = 0; f < FD; ++f) a += xs[hf][t][f] * cv(encW[f*HD + j]);
    hs[hf][t][j] = a;
    h11 = a;
  }
  __syncthreads();

  float kacc[TT], vacc[TT];
  #pragma unroll
  for (int t = 0; t < TT; ++t) { kacc[t] = 0.f; vacc[t] = 0.f; }
  float qacc = 0.f;
  for (int i = 0; i < HD; ++i) {
    float wk = cv(Wk[i*HD + j]);
    float wv = cv(Wv[i*HD + j]);
    float wq = cv(Wq[i*HD + j]);
    qacc += hs[hf][TT-1][i] * wq;
    #pragma unroll
    for (int t = 0; t < TT; ++t) {
      float hv = hs[hf][t][i];
      kacc[t] += hv * wk;
      vacc[t] += hv * wv;
    }
  }
  #pragma unroll
  for (int t = 0; t < TT; ++t) { ks[hf][t][j] = kacc[t]; vs[hf][t][j] = vacc[t]; }
  qs[hf][j] = qacc;
  __syncthreads();

  if (j < NH * TT) {
    int hh = j / TT, t = j - hh * TT;
    float a = 0.f;
    #pragma unroll
    for (int d = 0; d < DH; ++d) a += qs[hf][hh*DH + d] * ks[hf][t][hh*DH + d];
    lgs[hf][hh][t] = a * 0.17677669529663687f;
  }
  __syncthreads();
  if (j < NH) {
    float mx = -1e30f;
    #pragma unroll
    for (int t = 0; t < TT; ++t) mx = fmaxf(mx, lgs[hf][j][t]);
    float sm = 0.f;
    float ex[TT];
    #pragma unroll
    for (int t = 0; t < TT; ++t) { ex[t] = expf(lgs[hf][j][t] - mx); sm += ex[t]; }
    float inv = 1.f / sm;
    #pragma unroll
    for (int t = 0; t < TT; ++t) aw[hf][j][t] = ex[t] * inv;
  }
  __syncthreads();
  {
    int hh = j >> 5;
    float a = 0.f;
    #pragma unroll
    for (int t = 0; t < TT; ++t) a += aw[hf][hh][t] * vs[hf][t][j];
    aos[hf][j] = a;
  }
  __syncthreads();

  float o = 0.f;
  for (int i = 0; i < HD; ++i) o += aos[hf][i] * cv(Wo[i*HD + j]);
  float r1 = h11 + o;

  float mu, rstd;
  ln_stats(r1, hf, j, red8, mu, rstd);
  float h1 = (r1 - mu) * rstd * cv(l1g[j]) + cv(l1b[j]);
  h1s[hf][j] = h1;
  __syncthreads();

  float a0 = cv(fb1[j]), a1 = cv(fb1[j + HD]);
  for (int i = 0; i < HD; ++i) {
    float hv = h1s[hf][i];
    a0 += hv * cv(W1[i*FF + j]);
    a1 += hv * cv(W1[i*FF + HD + j]);
  }
  f1s[hf][j] = fmaxf(a0, 0.f);
  f1s[hf][j + HD] = fmaxf(a1, 0.f);
  __syncthreads();
  float f2 = cv(fb2[j]);
  for (int c = 0; c < FF; ++c) f2 += f1s[hf][c] * cv(W2[c*HD + j]);
  float r2 = h1 + f2;
  ln_stats(r2, hf, j, red8, mu, rstd);
  hlast[(size_t)m*HD + j] = (r2 - mu) * rstd * cv(l2g[j]) + cv(l2b[j]);
}

// ---------------- GAT1 ------------------------------------------------------
template<typename TI>
__global__ __launch_bounds__(128) void k_gat1_pre(
    const int* __restrict__ flag, int want,
    const float* __restrict__ hlast, const void* gW_, const void* asr_, const void* adr_,
    float* __restrict__ xl, float* __restrict__ s1, float* __restrict__ d1,
    float* __restrict__ acc, float* __restrict__ den)
{
  if (*flag != want) return;
  const TI* gW  = (const TI*)gW_;
  const TI* asr = (const TI*)asr_;
  const TI* adr = (const TI*)adr_;
  __shared__ float hrow[HD];
  int j = threadIdx.x, m = blockIdx.x;
  hrow[j] = hlast[(size_t)m*HD + j];
  __syncthreads();
  float a = 0.f;
  for (int i = 0; i < HD; ++i) a += hrow[i] * cv(gW[i*HD + j]);
  xl[(size_t)m*HD + j] = a;
  acc[(size_t)m*HD + j] = 0.f;
  float pa = a * cv(asr[j]);
  float pb = a * cv(adr[j]);
  #pragma unroll
  for (int off = 16; off > 0; off >>= 1) { pa += __shfl_xor(pa, off); pb += __shfl_xor(pb, off); }
  if ((j & 31) == 0) {
    int h = j >> 5;
    s1[m*NH + h] = pa;
    d1[m*NH + h] = pb;
    den[m*NH + h] = 0.f;
  }
}

__global__ __launch_bounds__(256) void k_gat1_edge(
    const int* __restrict__ e0, const int* __restrict__ e1,
    const float* __restrict__ s1, const float* __restrict__ d1,
    const float* __restrict__ xl, float* __restrict__ acc, float* __restrict__ den)
{
  int g = blockIdx.x * 8 + (threadIdx.x >> 5);
  int lane = threadIdx.x & 31;
  int h = g & 3, e = g >> 2;
  int b = e / EE, i = e - b * EE;
  int src = e0[i] + b * NN;
  int dst = e1[i] + b * NN;
  float eev = expf(lrelu(s1[src*NH + h] + d1[dst*NH + h]));
  if (lane == 0) atomicAdd(&den[dst*NH + h], eev);
  atomicAdd(&acc[(size_t)dst*HD + h*DH + lane],
            eev * xl[(size_t)src*HD + h*DH + lane]);
}

template<typename TI>
__global__ __launch_bounds__(128) void k_gat1_fin(
    const int* __restrict__ flag, int want,
    const float* __restrict__ xl, const float* __restrict__ s1, const float* __restrict__ d1,
    const float* __restrict__ acc, const float* __restrict__ den,
    const void* gb_, float* __restrict__ g1o)
{
  if (*flag != want) return;
  const TI* gb = (const TI*)gb_;
  int j = threadIdx.x, m = blockIdx.x, h = j >> 5;
  float es = expf(lrelu(s1[m*NH + h] + d1[m*NH + h]));
  float num = acc[(size_t)m*HD + j] + es * xl[(size_t)m*HD + j];
  float dn = den[m*NH + h] + es + 1e-16f;
  float v = num / dn + cv(gb[j]);
  g1o[(size_t)m*HD + j] = v > 0.f ? v : expm1f(v);
}

// ---------------- GAT2 ------------------------------------------------------
template<typename TI>
__global__ __launch_bounds__(64) void k_gat2_pre(
    const int* __restrict__ flag, int want,
    const float* __restrict__ g1o, const void* gW_, const void* asr_, const void* adr_,
    float* __restrict__ xl2, float* __restrict__ s2, float* __restrict__ d2,
    float* __restrict__ acc2, float* __restrict__ den2)
{
  if (*flag != want) return;
  const TI* gW  = (const TI*)gW_;
  const TI* asr = (const TI*)asr_;
  const TI* adr = (const TI*)adr_;
  __shared__ float grow[HD];
  int j = threadIdx.x, m = blockIdx.x;
  grow[j]      = g1o[(size_t)m*HD + j];
  grow[j + 64] = g1o[(size_t)m*HD + j + 64];
  __syncthreads();
  float a = 0.f;
  for (int i = 0; i < HD; ++i) a += grow[i] * cv(gW[i*GO + j]);
  xl2[(size_t)m*GO + j] = a;
  acc2[(size_t)m*GO + j] = 0.f;
  float pa = a * cv(asr[j]);
  float pb = a * cv(adr[j]);
  #pragma unroll
  for (int off = 32; off > 0; off >>= 1) { pa += __shfl_xor(pa, off); pb += __shfl_xor(pb, off); }
  if (j == 0) { s2[m] = pa; d2[m] = pb; den2[m] = 0.f; }
}

__global__ __launch_bounds__(256) void k_gat2_edge(
    const int* __restrict__ e0, const int* __restrict__ e1,
    const float* __restrict__ s2, const float* __restrict__ d2,
    const float* __restrict__ xl2, float* __restrict__ acc2, float* __restrict__ den2)
{
  int e = blockIdx.x * 4 + (threadIdx.x >> 6);
  int lane = threadIdx.x & 63;
  int b = e / EE, i = e - b * EE;
  int src = e0[i] + b * NN;
  int dst = e1[i] + b * NN;
  float eev = expf(lrelu(s2[src] + d2[dst]));
  if (lane == 0) atomicAdd(&den2[dst], eev);
  atomicAdd(&acc2[(size_t)dst*GO + lane], eev * xl2[(size_t)src*GO + lane]);
}

template<typename TI, typename TO>
__global__ __launch_bounds__(64) void k_gat2_fin(
    const int* __restrict__ flag, int want,
    const float* __restrict__ xl2, const float* __restrict__ s2, const float* __restrict__ d2,
    const float* __restrict__ acc2, const float* __restrict__ den2,
    const void* gb_, const void* oW_, const void* ob_, void* y_)
{
  if (*flag != want) return;
  const TI* gb = (const TI*)gb_;
  const TI* oW = (const TI*)oW_;
  const TI* ob = (const TI*)ob_;
  TO* y = (TO*)y_;
  __shared__ float g2s[GO];
  int j = threadIdx.x, m = blockIdx.x;
  float es = expf(lrelu(s2[m] + d2[m]));
  float num = acc2[(size_t)m*GO + j] + es * xl2[(size_t)m*GO + j];
  float dn = den2[m] + es + 1e-16f;
  g2s[j] = num / dn + cv(gb[j]);
  __syncthreads();
  if (j < HR) {
    float a = cv(ob[j]);
    #pragma unroll
    for (int o2 = 0; o2 < GO; ++o2) a += g2s[o2] * cv(oW[o2*HR + j]);
    int b = m / NN, n = m - b * NN;
    st(&y[((size_t)b*HR + j)*NN + n], a);
  }
}

// ---------------- launch ----------------------------------------------------
extern "C" void kernel_launch(void* const* d_in, const int* in_sizes, int n_in,
                              void* d_out, int out_size, void* d_ws, size_t ws_size,
                              hipStream_t stream)
{
  const int* ei = (const int*)d_in[2];
  const int* e0 = ei;
  const int* e1 = ei + EE;

  float* ws    = (float*)d_ws;
  float* hlast = ws;                  // 40000*128
  float* xl1   = ws + 5120000;        // 40000*128
  float* acc1  = ws + 10240000;       // 40000*128
  float* s1    = ws + 15360000;       // 40000*4
  float* d1    = ws + 15520000;       // 40000*4
  float* den1  = ws + 15680000;       // 40000*4
  int*   flag  = (int*)(ws + 15840000);
  unsigned short* Mt  = (unsigned short*)(ws + 15840016);  // 512*128 bf16
  unsigned short* Pt  = Mt + 65536;                        // 128*512 bf16
  unsigned short* W1t = Mt + 131072;                       // 256*128 bf16
  unsigned short* W2t = Mt + 163840;                       // 128*256 bf16
  float* encWf = (float*)(Mt + 196608);                    // 16*128
  float* encBf = encWf + 2048;
  float* fb1f  = encBf + 128;
  float* fb2f  = fb1f + 256;
  float* l1gf  = fb2f + 128;
  float* l1bf  = l1gf + 128;
  float* l2gf  = l1bf + 128;
  float* l2bf  = l2gf + 128;

  // phase-2 aliases (lifetimes disjoint)
  float* g1o  = hlast;
  float* xl2  = xl1;
  float* acc2 = acc1;
  float* s2 = s1; float* d2 = d1; float* den2 = den1;

  k_detect<<<1, 1, 0, stream>>>(d_in[0], flag);

  k_prep_mp<__hip_bfloat16><<<512, 256, 0, stream>>>(flag, 1,
      d_in[5], d_in[6], d_in[7], d_in[8], Mt, Pt);
  k_prep_w<__hip_bfloat16><<<268, 256, 0, stream>>>(flag, 1,
      d_in[3], d_in[4], d_in[11], d_in[12], d_in[13], d_in[14],
      d_in[9], d_in[10], d_in[15], d_in[16],
      W1t, W2t, encWf, encBf, fb1f, fb2f, l1gf, l1bf, l2gf, l2bf);

  k_xform<__hip_bfloat16><<<MM/4, 256, 0, stream>>>(flag, 1,
      d_in[0], d_in[1], Mt, Pt, W1t, W2t,
      encWf, encBf, fb1f, fb2f, l1gf, l1bf, l2gf, l2bf, hlast);

  // fp32 safety path (no-op when inputs are bf16)
  k_transformer<float><<<MM/2, 256, 0, stream>>>(flag, 0,
      d_in[0], d_in[1], d_in[3], d_in[4], d_in[5], d_in[6], d_in[7], d_in[8],
      d_in[9], d_in[10], d_in[11], d_in[12], d_in[13], d_in[14], d_in[15], d_in[16], hlast);

  k_gat1_pre<__hip_bfloat16><<<MM, 128, 0, stream>>>(flag, 1, hlast,
      d_in[17], d_in[18], d_in[19], xl1, s1, d1, acc1, den1);
  k_gat1_pre<float><<<MM, 128, 0, stream>>>(flag, 0, hlast,
      d_in[17], d_in[18], d_in[19], xl1, s1, d1, acc1, den1);

  k_gat1_edge<<<(BB*EE*NH)/8, 256, 0, stream>>>(e0, e1, s1, d1, xl1, acc1, den1);

  k_gat1_fin<__hip_bfloat16><<<MM, 128, 0, stream>>>(flag, 1, xl1, s1, d1, acc1, den1, d_in[20], g1o);
  k_gat1_fin<float><<<MM, 128, 0, stream>>>(flag, 0, xl1, s1, d1, acc1, den1, d_in[20], g1o);

  k_gat2_pre<__hip_bfloat16><<<MM, 64, 0, stream>>>(flag, 1, g1o,
      d_in[21], d_in[22], d_in[23], xl2, s2, d2, acc2, den2);
  k_gat2_pre<float><<<MM, 64, 0, stream>>>(flag, 0, g1o,
      d_in[21], d_in[22], d_in[23], xl2, s2, d2, acc2, den2);

  k_gat2_edge<<<(BB*EE)/4, 256, 0, stream>>>(e0, e1, s2, d2, xl2, acc2, den2);

  k_gat2_fin<__hip_bfloat16, __hip_bfloat16><<<MM, 64, 0, stream>>>(flag, 1,
      xl2, s2, d2, acc2, den2, d_in[24], d_in[25], d_in[26], d_out);
  k_gat2_fin<float, float><<<MM, 64, 0, stream>>>(flag, 0,
      xl2, s2, d2, acc2, den2, d_in[24], d_in[25], d_in[26], d_out);
}